// Round 1
// baseline (253.844 us; speedup 1.0000x reference)
//
#include <hip/hip_runtime.h>

#define K_SEL 103
#define TWO_PI 6.283185307179586f

// ---------------- K0: W2t[e*32+d], e = j*64+c, j in [0,33) ----------------
__global__ __launch_bounds__(256) void k0_w2t(const float* __restrict__ W2,
                                              const float* __restrict__ filt,
                                              float* __restrict__ W2t) {
    int t = blockIdx.x * 256 + threadIdx.x;
    if (t >= 2112 * 32) return;
    int d = t & 31;
    int e = t >> 5;
    int c = e & 63;
    int j = e >> 6;
    W2t[t] = (j < 32) ? W2[(c * 32 + d) * 32 + j] : filt[c * 32 + d];
}

// ---------------- K1: xl = x @ W_lin^T + b_lin  (16384 x 64) ----------------
__global__ __launch_bounds__(256) void k1_lin(const float* __restrict__ x,
                                              const float* __restrict__ W,
                                              const float* __restrict__ b,
                                              float* __restrict__ xl) {
    __shared__ float Wt[64 * 64];   // Wt[j*64+i] = W[i*64+j]
    for (int t = threadIdx.x; t < 4096; t += 256)
        Wt[(t & 63) * 64 + (t >> 6)] = W[t];
    __syncthreads();
    int i = threadIdx.x & 63;
    int sub = threadIdx.x >> 6;
    int r0 = blockIdx.x * 16 + sub * 4;
    float bi = b[i];
    float acc0 = bi, acc1 = bi, acc2 = bi, acc3 = bi;
    const float* xr = x + (size_t)r0 * 64;
    #pragma unroll 4
    for (int jj = 0; jj < 16; ++jj) {
        float4 v0 = *(const float4*)(xr + 0 * 64 + jj * 4);
        float4 v1 = *(const float4*)(xr + 1 * 64 + jj * 4);
        float4 v2 = *(const float4*)(xr + 2 * 64 + jj * 4);
        float4 v3 = *(const float4*)(xr + 3 * 64 + jj * 4);
        float w0 = Wt[(jj * 4 + 0) * 64 + i];
        float w1 = Wt[(jj * 4 + 1) * 64 + i];
        float w2 = Wt[(jj * 4 + 2) * 64 + i];
        float w3 = Wt[(jj * 4 + 3) * 64 + i];
        acc0 += v0.x * w0 + v0.y * w1 + v0.z * w2 + v0.w * w3;
        acc1 += v1.x * w0 + v1.y * w1 + v1.z * w2 + v1.w * w3;
        acc2 += v2.x * w0 + v2.y * w1 + v2.z * w2 + v2.w * w3;
        acc3 += v3.x * w0 + v3.y * w1 + v3.z * w2 + v3.w * w3;
    }
    xl[(size_t)(r0 + 0) * 64 + i] = acc0;
    xl[(size_t)(r0 + 1) * 64 + i] = acc1;
    xl[(size_t)(r0 + 2) * 64 + i] = acc2;
    xl[(size_t)(r0 + 3) * 64 + i] = acc3;
}

// ---------------- K2: per-query neighbor select + kernel-MLP ----------------
// Writes Hg[q][k][36]: j<32 -> gelu(mlp)*kd ; j==32 -> kd ; 33..35 -> 0
// Writes indg[q][k] = selected point index (rank-k by ascending edist).
__global__ __launch_bounds__(256) void k2_select(const float* __restrict__ pos,
                                                 const float* __restrict__ qpos,
                                                 const float* __restrict__ Bmat,
                                                 const float* __restrict__ W1,
                                                 const float* __restrict__ b1,
                                                 float* __restrict__ Hg,
                                                 int* __restrict__ indg) {
    const int q = blockIdx.x;
    const int tid = threadIdx.x;
    __shared__ unsigned long long keys[2048];
    __shared__ float W1s[1024];
    __shared__ float b1s[32];
    __shared__ float Bm[32];
    __shared__ float sred[128];

    for (int t = tid; t < 1024; t += 256) W1s[t] = W1[t];
    if (tid < 32) { b1s[tid] = b1[tid]; Bm[tid] = Bmat[tid]; }

    const float qp0 = qpos[q * 2 + 0];
    const float qp1 = qpos[q * 2 + 1];

    for (int v = tid; v < 2048; v += 256) {
        float d0 = qp0 - pos[v * 2 + 0];
        float d1 = qp1 - pos[v * 2 + 1];
        d0 += 0.5f; d0 -= floorf(d0); d0 -= 0.5f;
        d1 += 0.5f; d1 -= floorf(d1); d1 -= 0.5f;
        float e = d0 * d0 + d1 * d1;
        keys[v] = (((unsigned long long)__float_as_uint(e)) << 32) | (unsigned)v;
    }
    // bitonic sort, ascending by (edist bits, index) -- matches top_k tie-break
    for (int kk = 2; kk <= 2048; kk <<= 1) {
        for (int j = kk >> 1; j > 0; j >>= 1) {
            __syncthreads();
            for (int i = tid; i < 2048; i += 256) {
                int ixj = i ^ j;
                if (ixj > i) {
                    unsigned long long a = keys[i];
                    unsigned long long bb = keys[ixj];
                    bool up = ((i & kk) == 0);
                    if ((a > bb) == up) { keys[i] = bb; keys[ixj] = a; }
                }
            }
        }
    }
    __syncthreads();

    const float e_min = __uint_as_float((unsigned)(keys[0] >> 32));
    const float e_max = __uint_as_float((unsigned)(keys[K_SEL - 1] >> 32));
    const float denom = (e_max - e_min) + 1e-8f;

    float w = 0.0f;
    int v = 0;
    if (tid < K_SEL) {
        unsigned long long kv = keys[tid];
        v = (int)(unsigned)(kv & 0xffffffffull);
        float e = __uint_as_float((unsigned)(kv >> 32));
        w = expf(-(e - e_min) / denom);
    }
    if (tid < 128) sred[tid] = (tid < K_SEL) ? w : 0.0f;
    __syncthreads();
    for (int s = 64; s > 0; s >>= 1) {
        if (tid < s) sred[tid] += sred[tid + s];
        __syncthreads();
    }
    const float total = sred[0];

    if (tid < K_SEL) {
        float kd = w / total;
        float d0 = qp0 - pos[v * 2 + 0];
        float d1 = qp1 - pos[v * 2 + 1];
        d0 += 0.5f; d0 -= floorf(d0); d0 -= 0.5f;
        d1 += 0.5f; d1 -= floorf(d1); d1 -= 0.5f;
        float kf[32];
        #pragma unroll
        for (int f = 0; f < 16; ++f) {
            float pr = TWO_PI * (d0 * Bm[f] + d1 * Bm[16 + f]);
            kf[f] = sinf(pr);
            kf[16 + f] = cosf(pr);
        }
        float* hout = Hg + ((size_t)q * K_SEL + tid) * 36;
        #pragma unroll 4
        for (int i = 0; i < 32; ++i) {
            float pre = b1s[i];
            #pragma unroll
            for (int jf = 0; jf < 32; ++jf) pre += kf[jf] * W1s[i * 32 + jf];
            float g = 0.5f * pre * (1.0f + erff(pre * 0.70710678118654752f));
            hout[i] = g * kd;
        }
        hout[32] = kd;
        hout[33] = 0.0f; hout[34] = 0.0f; hout[35] = 0.0f;
        indg[q * K_SEL + tid] = v;
    }
}

// ---------------- K3: gather + Z-GEMM + output GEMM (fused per query) -------
// z[bt,j',c] = sum_k H[k,j'] * xl[bt, ind[k], c]   (33 x 64 per (q,bt))
// out[bt,q,d] = sum_{j',c} W2t[(j'*64+c)*32+d] * z[bt,j',c] + bias[d]
__global__ __launch_bounds__(256) void k3_main(const float* __restrict__ xl,
                                               const float* __restrict__ Hg,
                                               const int* __restrict__ indg,
                                               const float* __restrict__ W2t,
                                               const float* __restrict__ bias,
                                               float* __restrict__ out) {
    const int q = blockIdx.x;
    const int tid = threadIdx.x;

    __shared__ float smem[14524];      // Hs | Xg | Zs(2 bt)  (58 KB)
    __shared__ int ind_s[K_SEL];
    float* Hs = smem;                  // 103*36 = 3708
    float* Xg = smem + 3708;           // 103*64 = 6592
    float* Zs = smem + 10300;          // 2*2112 = 4224
    float* red = smem + 3708;          // 8192 floats, aliases Xg+Zs (used last)

    for (int t = tid; t < K_SEL * 36; t += 256) Hs[t] = Hg[(size_t)q * (K_SEL * 36) + t];
    for (int t = tid; t < K_SEL; t += 256) ind_s[t] = indg[q * K_SEL + t];

    const int c16 = tid & 15;
    const int jg = tid >> 4;       // 0..15 (GEMM1 active: jg < 9)
    const int j0 = jg * 4;

    const int d4g = tid & 7;
    const int eg = tid >> 3;       // 0..31
    const int d0 = d4g * 4;
    const int ebase = (eg < 16) ? eg * 68 : (1088 + (eg - 16) * 64);
    const int elen = (eg < 16) ? 68 : 64;

    float acc[8][4];
    #pragma unroll
    for (int bt = 0; bt < 8; ++bt)
        #pragma unroll
        for (int i2 = 0; i2 < 4; ++i2) acc[bt][i2] = 0.0f;

    #pragma unroll
    for (int btp = 0; btp < 4; ++btp) {
        #pragma unroll
        for (int sub = 0; sub < 2; ++sub) {
            const int bt = btp * 2 + sub;
            __syncthreads();
            // gather Xg[k][c] = xl[bt, ind[k], c]  (float4, coalesced)
            const float* xb = xl + (size_t)bt * 2048 * 64;
            for (int t = tid; t < K_SEL * 16; t += 256) {
                int k = t >> 4, cq = t & 15;
                float4 vv = *(const float4*)(xb + (size_t)ind_s[k] * 64 + cq * 4);
                *(float4*)(&Xg[k * 64 + cq * 4]) = vv;
            }
            __syncthreads();
            // GEMM1: Zs[sub][j'][c] = sum_k Hs[k][j'] * Xg[k][c]
            if (jg < 9) {
                float a00=0,a01=0,a02=0,a03=0, a10=0,a11=0,a12=0,a13=0;
                float a20=0,a21=0,a22=0,a23=0, a30=0,a31=0,a32=0,a33=0;
                for (int k = 0; k < K_SEL; ++k) {
                    float4 xv = *(const float4*)(&Xg[k * 64 + c16 * 4]);
                    float4 hv = *(const float4*)(&Hs[k * 36 + j0]);
                    a00 += hv.x * xv.x; a01 += hv.x * xv.y; a02 += hv.x * xv.z; a03 += hv.x * xv.w;
                    a10 += hv.y * xv.x; a11 += hv.y * xv.y; a12 += hv.y * xv.z; a13 += hv.y * xv.w;
                    a20 += hv.z * xv.x; a21 += hv.z * xv.y; a22 += hv.z * xv.z; a23 += hv.z * xv.w;
                    a30 += hv.w * xv.x; a31 += hv.w * xv.y; a32 += hv.w * xv.z; a33 += hv.w * xv.w;
                }
                float* zb = Zs + sub * 2112 + j0 * 64 + c16 * 4;
                *(float4*)(zb + 0 * 64) = make_float4(a00, a01, a02, a03);
                if (jg < 8) {
                    *(float4*)(zb + 1 * 64) = make_float4(a10, a11, a12, a13);
                    *(float4*)(zb + 2 * 64) = make_float4(a20, a21, a22, a23);
                    *(float4*)(zb + 3 * 64) = make_float4(a30, a31, a32, a33);
                }
            }
        }
        __syncthreads();
        // GEMM2 partial for this bt-pair over this thread's e-slice
        for (int ii = 0; ii < elen; ii += 4) {
            const int e = ebase + ii;
            float4 w0 = *(const float4*)(W2t + (size_t)(e + 0) * 32 + d0);
            float4 w1 = *(const float4*)(W2t + (size_t)(e + 1) * 32 + d0);
            float4 w2 = *(const float4*)(W2t + (size_t)(e + 2) * 32 + d0);
            float4 w3 = *(const float4*)(W2t + (size_t)(e + 3) * 32 + d0);
            #pragma unroll
            for (int sub = 0; sub < 2; ++sub) {
                const int bt = btp * 2 + sub;
                float4 z = *(const float4*)(&Zs[sub * 2112 + e]);
                acc[bt][0] += z.x * w0.x + z.y * w1.x + z.z * w2.x + z.w * w3.x;
                acc[bt][1] += z.x * w0.y + z.y * w1.y + z.z * w2.y + z.w * w3.y;
                acc[bt][2] += z.x * w0.z + z.y * w1.z + z.z * w2.z + z.w * w3.z;
                acc[bt][3] += z.x * w0.w + z.y * w1.w + z.z * w2.w + z.w * w3.w;
            }
        }
    }
    __syncthreads();   // all Zs reads done; safe to write aliased red
    #pragma unroll
    for (int bt = 0; bt < 8; ++bt)
        #pragma unroll
        for (int i2 = 0; i2 < 4; ++i2)
            red[eg * 256 + bt * 32 + d0 + i2] = acc[bt][i2];
    __syncthreads();
    {
        const int bt = tid >> 5;
        const int d = tid & 31;
        float s = bias[d];
        #pragma unroll
        for (int p = 0; p < 32; ++p) s += red[p * 256 + tid];
        out[((size_t)bt * 512 + q) * 32 + d] = s;
    }
}

// ---------------------------------------------------------------------------
extern "C" void kernel_launch(void* const* d_in, const int* in_sizes, int n_in,
                              void* d_out, int out_size, void* d_ws, size_t ws_size,
                              hipStream_t stream) {
    const float* x     = (const float*)d_in[0];   // (2,4,2048,64)
    const float* pos   = (const float*)d_in[1];   // (2048,2)
    const float* qpos  = (const float*)d_in[2];   // (512,2)
    const float* W_lin = (const float*)d_in[3];   // (64,64)
    const float* b_lin = (const float*)d_in[4];   // (64)
    const float* Bmat  = (const float*)d_in[5];   // (2,16)
    const float* W1    = (const float*)d_in[6];   // (32,32)
    const float* b1    = (const float*)d_in[7];   // (32)
    const float* W2    = (const float*)d_in[8];   // (2048,32)
    const float* filt  = (const float*)d_in[9];   // (2048)
    const float* bias  = (const float*)d_in[10];  // (32)
    float* out = (float*)d_out;

    float* ws   = (float*)d_ws;
    float* xl   = ws;                      // 16384*64    = 1048576 floats
    float* Hg   = ws + 1048576;            // 512*103*36  = 1898496 floats
    int*   indg = (int*)(ws + 2947072);    // 512*103     = 52736 ints
    float* W2t  = ws + 2999808;            // 2112*32     = 67584 floats

    k0_w2t<<<264, 256, 0, stream>>>(W2, filt, W2t);
    k1_lin<<<1024, 256, 0, stream>>>(x, W_lin, b_lin, xl);
    k2_select<<<512, 256, 0, stream>>>(pos, qpos, Bmat, W1, b1, Hg, indg);
    k3_main<<<512, 256, 0, stream>>>(xl, Hg, indg, W2t, bias, out);
}

// Round 2
// 196.368 us; speedup vs baseline: 1.2927x; 1.2927x over previous
//
#include <hip/hip_runtime.h>

#define K_SEL 103
#define TWO_PI 6.283185307179586f

// ---------------- K0: W2t[e*32+d], e = j*64+c, j in [0,33) ----------------
__global__ __launch_bounds__(256) void k0_w2t(const float* __restrict__ W2,
                                              const float* __restrict__ filt,
                                              float* __restrict__ W2t) {
    int t = blockIdx.x * 256 + threadIdx.x;
    if (t >= 2112 * 32) return;
    int d = t & 31;
    int e = t >> 5;
    int c = e & 63;
    int j = e >> 6;
    W2t[t] = (j < 32) ? W2[(c * 32 + d) * 32 + j] : filt[c * 32 + d];
}

// ---------------- K1: xl = x @ W_lin^T + b_lin  (16384 x 64) ----------------
__global__ __launch_bounds__(256) void k1_lin(const float* __restrict__ x,
                                              const float* __restrict__ W,
                                              const float* __restrict__ b,
                                              float* __restrict__ xl) {
    __shared__ float Wt[64 * 64];   // Wt[j*64+i] = W[i*64+j]
    for (int t = threadIdx.x; t < 4096; t += 256)
        Wt[(t & 63) * 64 + (t >> 6)] = W[t];
    __syncthreads();
    int i = threadIdx.x & 63;
    int sub = threadIdx.x >> 6;
    int r0 = blockIdx.x * 16 + sub * 4;
    float bi = b[i];
    float acc0 = bi, acc1 = bi, acc2 = bi, acc3 = bi;
    const float* xr = x + (size_t)r0 * 64;
    #pragma unroll 4
    for (int jj = 0; jj < 16; ++jj) {
        float4 v0 = *(const float4*)(xr + 0 * 64 + jj * 4);
        float4 v1 = *(const float4*)(xr + 1 * 64 + jj * 4);
        float4 v2 = *(const float4*)(xr + 2 * 64 + jj * 4);
        float4 v3 = *(const float4*)(xr + 3 * 64 + jj * 4);
        float w0 = Wt[(jj * 4 + 0) * 64 + i];
        float w1 = Wt[(jj * 4 + 1) * 64 + i];
        float w2 = Wt[(jj * 4 + 2) * 64 + i];
        float w3 = Wt[(jj * 4 + 3) * 64 + i];
        acc0 += v0.x * w0 + v0.y * w1 + v0.z * w2 + v0.w * w3;
        acc1 += v1.x * w0 + v1.y * w1 + v1.z * w2 + v1.w * w3;
        acc2 += v2.x * w0 + v2.y * w1 + v2.z * w2 + v2.w * w3;
        acc3 += v3.x * w0 + v3.y * w1 + v3.z * w2 + v3.w * w3;
    }
    xl[(size_t)(r0 + 0) * 64 + i] = acc0;
    xl[(size_t)(r0 + 1) * 64 + i] = acc1;
    xl[(size_t)(r0 + 2) * 64 + i] = acc2;
    xl[(size_t)(r0 + 3) * 64 + i] = acc3;
}

// ---------------- K2: per-query neighbor select (radix-select) + kernel-MLP -
// Selection set = 103 smallest edists (ties by smallest index, matching
// top_k). Slot order is arbitrary: all downstream consumers are
// order-invariant sums over k. e_max = rank-102 value from radix select.
__global__ __launch_bounds__(256) void k2_select(const float* __restrict__ pos,
                                                 const float* __restrict__ qpos,
                                                 const float* __restrict__ Bmat,
                                                 const float* __restrict__ W1,
                                                 const float* __restrict__ b1,
                                                 float* __restrict__ Hg,
                                                 int* __restrict__ indg) {
    const int q = blockIdx.x;
    const int tid = threadIdx.x;

    __shared__ unsigned ebits[2048];   // 8 KB, monotone float bits (e >= 0)
    __shared__ unsigned hist[256];
    __shared__ unsigned scan_s[256];
    __shared__ float W1s[1024];
    __shared__ float b1s[32];
    __shared__ float Bm[32];
    __shared__ float sred[128];
    __shared__ int   sel_v[K_SEL];
    __shared__ float sel_e[K_SEL];     // later reused to hold w
    __shared__ int   eq_idx[64];
    __shared__ int   counters[2];      // n_less, n_eq
    __shared__ unsigned sel_info[2];   // bin, excl-prefix

    for (int t = tid; t < 1024; t += 256) W1s[t] = W1[t];
    if (tid < 32) { b1s[tid] = b1[tid]; Bm[tid] = Bmat[tid]; }
    if (tid < 2)  counters[tid] = 0;

    const float qp0 = qpos[q * 2 + 0];
    const float qp1 = qpos[q * 2 + 1];

    for (int v = tid; v < 2048; v += 256) {
        float d0 = qp0 - pos[v * 2 + 0];
        float d1 = qp1 - pos[v * 2 + 1];
        d0 += 0.5f; d0 -= floorf(d0); d0 -= 0.5f;
        d1 += 0.5f; d1 -= floorf(d1); d1 -= 0.5f;
        float e = d0 * d0 + d1 * d1;
        ebits[v] = __float_as_uint(e);
    }

    // ---- 4-pass radix select: exact bits of the rank-102 (0-based) element
    unsigned prefix = 0;
    int R = K_SEL - 1;                 // 102
    #pragma unroll
    for (int pass = 3; pass >= 0; --pass) {
        const int shift = pass * 8;
        __syncthreads();
        hist[tid] = 0;
        __syncthreads();
        for (int v = tid; v < 2048; v += 256) {
            unsigned b = ebits[v];
            bool ok = (pass == 3) || ((b >> (shift + 8)) == (prefix >> (shift + 8)));
            if (ok) atomicAdd(&hist[(b >> shift) & 255u], 1u);
        }
        __syncthreads();
        // inclusive scan (Hillis-Steele) of hist -> scan_s
        scan_s[tid] = hist[tid];
        __syncthreads();
        #pragma unroll
        for (int s = 1; s < 256; s <<= 1) {
            unsigned add = (tid >= s) ? scan_s[tid - s] : 0u;
            __syncthreads();
            scan_s[tid] += add;
            __syncthreads();
        }
        unsigned incl = scan_s[tid];
        unsigned excl = incl - hist[tid];
        if ((int)excl <= R && R < (int)incl) {
            sel_info[0] = (unsigned)tid;
            sel_info[1] = excl;
        }
        __syncthreads();
        prefix |= sel_info[0] << shift;
        R -= (int)sel_info[1];
    }
    const unsigned thr = prefix;       // bits of rank-102 element
    // R = rank within equal-valued elements -> take R+1 of them (smallest idx)

    // ---- compaction (slot order arbitrary)
    __syncthreads();
    for (int v = tid; v < 2048; v += 256) {
        unsigned b = ebits[v];
        if (b < thr) {
            int s = atomicAdd(&counters[0], 1);
            sel_v[s] = v;
            sel_e[s] = __uint_as_float(b);
        } else if (b == thr) {
            int s = atomicAdd(&counters[1], 1);
            if (s < 64) eq_idx[s] = v;
        }
    }
    __syncthreads();
    if (tid == 0) {
        int L = counters[0];
        int need = K_SEL - L;          // == R+1
        int ne = counters[1]; if (ne > 64) ne = 64;
        // insertion sort tiny equal-set by index ascending
        for (int i = 1; i < ne; ++i) {
            int key = eq_idx[i], j2 = i - 1;
            while (j2 >= 0 && eq_idx[j2] > key) { eq_idx[j2 + 1] = eq_idx[j2]; --j2; }
            eq_idx[j2 + 1] = key;
        }
        float ev = __uint_as_float(thr);
        for (int i = 0; i < need; ++i) { sel_v[L + i] = eq_idx[i]; sel_e[L + i] = ev; }
    }
    __syncthreads();

    // ---- e_min (global min = rank-0, guaranteed in selected set)
    if (tid < 128) {
        float a = (tid < K_SEL) ? sel_e[tid] : 1e30f;
        sred[tid] = a;
    }
    __syncthreads();
    for (int s = 64; s > 0; s >>= 1) {
        if (tid < s) sred[tid] = fminf(sred[tid], sred[tid + s]);
        __syncthreads();
    }
    const float e_min = sred[0];
    const float e_max = __uint_as_float(thr);
    const float denom = (e_max - e_min) + 1e-8f;
    __syncthreads();                   // sred reused below

    // ---- softmax weights
    float w = 0.0f;
    if (tid < K_SEL) {
        w = __expf(-(sel_e[tid] - e_min) / denom);
    }
    __syncthreads();
    if (tid < K_SEL) sel_e[tid] = w;   // overwrite own slot: e no longer needed
    if (tid < 128) sred[tid] = (tid < K_SEL) ? w : 0.0f;
    __syncthreads();
    for (int s = 64; s > 0; s >>= 1) {
        if (tid < s) sred[tid] += sred[tid + s];
        __syncthreads();
    }
    const float total = sred[0];

    // ---- RFF + MLP: 2 threads per k (16 outputs each)
    if (tid < 2 * K_SEL) {
        const int k = tid >> 1;
        const int io = (tid & 1) * 16;
        const int v = sel_v[k];
        const float kd = sel_e[k] / total;
        float d0 = qp0 - pos[v * 2 + 0];
        float d1 = qp1 - pos[v * 2 + 1];
        d0 += 0.5f; d0 -= floorf(d0); d0 -= 0.5f;
        d1 += 0.5f; d1 -= floorf(d1); d1 -= 0.5f;
        float kf[32];
        #pragma unroll
        for (int f = 0; f < 16; ++f) {
            float pr = TWO_PI * (d0 * Bm[f] + d1 * Bm[16 + f]);
            kf[f] = sinf(pr);
            kf[16 + f] = cosf(pr);
        }
        float* hout = Hg + ((size_t)q * K_SEL + k) * 36;
        #pragma unroll 4
        for (int i = io; i < io + 16; ++i) {
            float pre = b1s[i];
            #pragma unroll
            for (int jf = 0; jf < 32; ++jf) pre += kf[jf] * W1s[i * 32 + jf];
            float g = 0.5f * pre * (1.0f + erff(pre * 0.70710678118654752f));
            hout[i] = g * kd;
        }
        if ((tid & 1) == 0) {
            hout[32] = kd;
            hout[33] = 0.0f; hout[34] = 0.0f; hout[35] = 0.0f;
            indg[q * K_SEL + k] = v;
        }
    }
}

// ---------------- K3: gather + Z-GEMM + output GEMM (fused per query) -------
// z[bt,j',c] = sum_k H[k,j'] * xl[bt, ind[k], c]   (33 x 64 per (q,bt))
// out[bt,q,d] = sum_{j',c} W2t[(j'*64+c)*32+d] * z[bt,j',c] + bias[d]
__global__ __launch_bounds__(256) void k3_main(const float* __restrict__ xl,
                                               const float* __restrict__ Hg,
                                               const int* __restrict__ indg,
                                               const float* __restrict__ W2t,
                                               const float* __restrict__ bias,
                                               float* __restrict__ out) {
    const int q = blockIdx.x;
    const int tid = threadIdx.x;

    __shared__ float smem[14524];      // Hs | Xg | Zs(2 bt)  (58 KB)
    __shared__ int ind_s[K_SEL];
    float* Hs = smem;                  // 103*36 = 3708
    float* Xg = smem + 3708;           // 103*64 = 6592
    float* Zs = smem + 10300;          // 2*2112 = 4224
    float* red = smem + 3708;          // 8192 floats, aliases Xg+Zs (used last)

    for (int t = tid; t < K_SEL * 36; t += 256) Hs[t] = Hg[(size_t)q * (K_SEL * 36) + t];
    for (int t = tid; t < K_SEL; t += 256) ind_s[t] = indg[q * K_SEL + t];

    const int c16 = tid & 15;
    const int jg = tid >> 4;       // 0..15 (GEMM1 active: jg < 9)
    const int j0 = jg * 4;

    const int d4g = tid & 7;
    const int eg = tid >> 3;       // 0..31
    const int d0 = d4g * 4;
    const int ebase = (eg < 16) ? eg * 68 : (1088 + (eg - 16) * 64);
    const int elen = (eg < 16) ? 68 : 64;

    float acc[8][4];
    #pragma unroll
    for (int bt = 0; bt < 8; ++bt)
        #pragma unroll
        for (int i2 = 0; i2 < 4; ++i2) acc[bt][i2] = 0.0f;

    #pragma unroll
    for (int btp = 0; btp < 4; ++btp) {
        #pragma unroll
        for (int sub = 0; sub < 2; ++sub) {
            const int bt = btp * 2 + sub;
            __syncthreads();
            // gather Xg[k][c] = xl[bt, ind[k], c]  (float4, coalesced)
            const float* xb = xl + (size_t)bt * 2048 * 64;
            for (int t = tid; t < K_SEL * 16; t += 256) {
                int k = t >> 4, cq = t & 15;
                float4 vv = *(const float4*)(xb + (size_t)ind_s[k] * 64 + cq * 4);
                *(float4*)(&Xg[k * 64 + cq * 4]) = vv;
            }
            __syncthreads();
            // GEMM1: Zs[sub][j'][c] = sum_k Hs[k][j'] * Xg[k][c]
            if (jg < 9) {
                float a00=0,a01=0,a02=0,a03=0, a10=0,a11=0,a12=0,a13=0;
                float a20=0,a21=0,a22=0,a23=0, a30=0,a31=0,a32=0,a33=0;
                for (int k = 0; k < K_SEL; ++k) {
                    float4 xv = *(const float4*)(&Xg[k * 64 + c16 * 4]);
                    float4 hv = *(const float4*)(&Hs[k * 36 + j0]);
                    a00 += hv.x * xv.x; a01 += hv.x * xv.y; a02 += hv.x * xv.z; a03 += hv.x * xv.w;
                    a10 += hv.y * xv.x; a11 += hv.y * xv.y; a12 += hv.y * xv.z; a13 += hv.y * xv.w;
                    a20 += hv.z * xv.x; a21 += hv.z * xv.y; a22 += hv.z * xv.z; a23 += hv.z * xv.w;
                    a30 += hv.w * xv.x; a31 += hv.w * xv.y; a32 += hv.w * xv.z; a33 += hv.w * xv.w;
                }
                float* zb = Zs + sub * 2112 + j0 * 64 + c16 * 4;
                *(float4*)(zb + 0 * 64) = make_float4(a00, a01, a02, a03);
                if (jg < 8) {
                    *(float4*)(zb + 1 * 64) = make_float4(a10, a11, a12, a13);
                    *(float4*)(zb + 2 * 64) = make_float4(a20, a21, a22, a23);
                    *(float4*)(zb + 3 * 64) = make_float4(a30, a31, a32, a33);
                }
            }
        }
        __syncthreads();
        // GEMM2 partial for this bt-pair over this thread's e-slice
        for (int ii = 0; ii < elen; ii += 4) {
            const int e = ebase + ii;
            float4 w0 = *(const float4*)(W2t + (size_t)(e + 0) * 32 + d0);
            float4 w1 = *(const float4*)(W2t + (size_t)(e + 1) * 32 + d0);
            float4 w2 = *(const float4*)(W2t + (size_t)(e + 2) * 32 + d0);
            float4 w3 = *(const float4*)(W2t + (size_t)(e + 3) * 32 + d0);
            #pragma unroll
            for (int sub = 0; sub < 2; ++sub) {
                const int bt = btp * 2 + sub;
                float4 z = *(const float4*)(&Zs[sub * 2112 + e]);
                acc[bt][0] += z.x * w0.x + z.y * w1.x + z.z * w2.x + z.w * w3.x;
                acc[bt][1] += z.x * w0.y + z.y * w1.y + z.z * w2.y + z.w * w3.y;
                acc[bt][2] += z.x * w0.z + z.y * w1.z + z.z * w2.z + z.w * w3.z;
                acc[bt][3] += z.x * w0.w + z.y * w1.w + z.z * w2.w + z.w * w3.w;
            }
        }
    }
    __syncthreads();   // all Zs reads done; safe to write aliased red
    #pragma unroll
    for (int bt = 0; bt < 8; ++bt)
        #pragma unroll
        for (int i2 = 0; i2 < 4; ++i2)
            red[eg * 256 + bt * 32 + d0 + i2] = acc[bt][i2];
    __syncthreads();
    {
        const int bt = tid >> 5;
        const int d = tid & 31;
        float s = bias[d];
        #pragma unroll
        for (int p = 0; p < 32; ++p) s += red[p * 256 + tid];
        out[((size_t)bt * 512 + q) * 32 + d] = s;
    }
}

// ---------------------------------------------------------------------------
extern "C" void kernel_launch(void* const* d_in, const int* in_sizes, int n_in,
                              void* d_out, int out_size, void* d_ws, size_t ws_size,
                              hipStream_t stream) {
    const float* x     = (const float*)d_in[0];   // (2,4,2048,64)
    const float* pos   = (const float*)d_in[1];   // (2048,2)
    const float* qpos  = (const float*)d_in[2];   // (512,2)
    const float* W_lin = (const float*)d_in[3];   // (64,64)
    const float* b_lin = (const float*)d_in[4];   // (64)
    const float* Bmat  = (const float*)d_in[5];   // (2,16)
    const float* W1    = (const float*)d_in[6];   // (32,32)
    const float* b1    = (const float*)d_in[7];   // (32)
    const float* W2    = (const float*)d_in[8];   // (2048,32)
    const float* filt  = (const float*)d_in[9];   // (2048)
    const float* bias  = (const float*)d_in[10];  // (32)
    float* out = (float*)d_out;

    float* ws   = (float*)d_ws;
    float* xl   = ws;                      // 16384*64    = 1048576 floats
    float* Hg   = ws + 1048576;            // 512*103*36  = 1898496 floats
    int*   indg = (int*)(ws + 2947072);    // 512*103     = 52736 ints
    float* W2t  = ws + 2999808;            // 2112*32     = 67584 floats

    k0_w2t<<<264, 256, 0, stream>>>(W2, filt, W2t);
    k1_lin<<<1024, 256, 0, stream>>>(x, W_lin, b_lin, xl);
    k2_select<<<512, 256, 0, stream>>>(pos, qpos, Bmat, W1, b1, Hg, indg);
    k3_main<<<512, 256, 0, stream>>>(xl, Hg, indg, W2t, bias, out);
}